// Round 5
// baseline (189.554 us; speedup 1.0000x reference)
//
#include <hip/hip_runtime.h>
#include <math.h>

#define BH   32
#define NSEQ 2048
#define DH   64
#define NH   16
#define LOG2E 1.44269504088896f

typedef _Float16 f16x8 __attribute__((ext_vector_type(8)));
typedef __fp16   fp16x2 __attribute__((ext_vector_type(2)));
typedef float    f32x16v __attribute__((ext_vector_type(16)));

#if __has_builtin(__builtin_amdgcn_exp2f)
#define EXP2F(x) __builtin_amdgcn_exp2f(x)
#else
#define EXP2F(x) exp2f(x)
#endif

static __device__ __forceinline__ unsigned packh_rne(float a, float b) {
    union { _Float16 h[2]; unsigned u; } x;
    x.h[0] = (_Float16)a; x.h[1] = (_Float16)b;
    return x.u;
}
static __device__ __forceinline__ unsigned pkrtz(float a, float b) {
    fp16x2 r = __builtin_amdgcn_cvt_pkrtz(a, b);
    return __builtin_bit_cast(unsigned, r);
}
#if __has_builtin(__builtin_amdgcn_perm)
#define PERM(a, b, s) __builtin_amdgcn_perm((a), (b), (s))
#else
static __device__ __forceinline__ unsigned PERM(unsigned a, unsigned b, unsigned s) {
    if (s == 0x05040100u) return (b & 0xffffu) | (a << 16);
    return (b >> 16) | (a & 0xffff0000u);
}
#endif

// ---------------- fused prep: q-norm/rope, k-norm/rope, v-pack ---------------
// grid.x: [0,8192) q rows, [8192,16384) k rows, [16384,17408) v tiles.
__global__ __launch_bounds__(256) void prep_all(
    const float* __restrict__ q, const float* __restrict__ k, const float* __restrict__ v,
    const float* __restrict__ qs, const float* __restrict__ ksc,
    unsigned* __restrict__ qh, unsigned* __restrict__ kh, unsigned* __restrict__ vt2) {
    const int bid = blockIdx.x;
    const int t = threadIdx.x;
    if (bid < 16384) {
        const bool isq = bid < 8192;
        const float* in = isq ? q : k;
        const float* sc = isq ? qs : ksc;
        unsigned* outp  = isq ? qh : kh;
        const float smul = isq ? 0.125f * LOG2E : 1.0f;
        const int sb = bid & 8191;
        __shared__ float2 tab[8][32];
        {
            int pr = t >> 5, p = t & 31;
            int pos = (sb * 8 + pr) & (NSEQ - 1);
            float infr = exp2f(-(float)p * (13.287712379549449f / 32.0f));
            float sn, cs;
            sincosf((float)pos * infr, &sn, &cs);
            tab[pr][p] = make_float2(cs, sn);
        }
        __syncthreads();
        const int w = t >> 6, lane = t & 63;
        const int c = lane & 31, hfr = lane >> 5;
        const int rl = w * 2 + hfr;
        const int row = sb * 8 + rl;
        float2 x2 = *(const float2*)(in + (size_t)row * DH + 2 * c);
        float ss = x2.x * x2.x + x2.y * x2.y;
        #pragma unroll
        for (int off = 16; off > 0; off >>= 1) ss += __shfl_xor(ss, off);
        float inv = 1.0f / fmaxf(sqrtf(ss), 1e-12f);
        float2 s2 = *(const float2*)(sc + 2 * c);
        float t0 = x2.x * inv * s2.x;
        float t1 = x2.y * inv * s2.y;
        float p0 = __shfl_xor(t0, 16);
        float p1 = __shfl_xor(t1, 16);
        float r0 = (c < 16) ? -p0 : p0;
        float r1 = (c < 16) ? -p1 : p1;
        float4 cc = *(const float4*)&tab[rl][(2 * c) & 31];
        float o0 = (t0 * cc.x + r0 * cc.y) * smul;
        float o1 = (t1 * cc.z + r1 * cc.w) * smul;
        outp[row * 32 + c] = packh_rne(o0, o1);
    } else {
        const int sb = bid - 16384;
        const int kt = sb & 31, bh = sb >> 5;
        const int r = t & 63, ch = t >> 6;
        const float* src = v + ((size_t)bh * NSEQ + kt * 64 + r) * DH + ch * 16;
        float4 a = *(const float4*)(src + 0);
        float4 b = *(const float4*)(src + 4);
        float4 c2 = *(const float4*)(src + 8);
        float4 d2 = *(const float4*)(src + 12);
        unsigned* dst = vt2 + ((size_t)bh * 32 + ch * 8) * NSEQ + kt * 64 + r;
        dst[0 * NSEQ] = packh_rne(a.x, a.y);
        dst[1 * NSEQ] = packh_rne(a.z, a.w);
        dst[2 * NSEQ] = packh_rne(b.x, b.y);
        dst[3 * NSEQ] = packh_rne(b.z, b.w);
        dst[4 * NSEQ] = packh_rne(c2.x, c2.y);
        dst[5 * NSEQ] = packh_rne(c2.z, c2.w);
        dst[6 * NSEQ] = packh_rne(d2.x, d2.y);
        dst[7 * NSEQ] = packh_rne(d2.z, d2.w);
    }
}

// ---------------- flash attention: split-K in-WG, f16 MFMA 32x32x16 ----------
// WG 512 = 8 waves. Waves 0-3 (kh=0): keys [0,1024); waves 4-7 (kh=1): [1024,2048).
// Wave wq=w&3 owns qrows qb*128 + wq*32 + c. 32-key tiles, double-buffered LDS.
// Fixed-max softmax -> partials combine as plain sums via LDS epilogue.
__global__ __launch_bounds__(512, 4) void attn_kernel(
    const unsigned* __restrict__ qh, const unsigned* __restrict__ khg,
    const unsigned* __restrict__ vt2, float* __restrict__ out) {

    __shared__ __align__(16) unsigned char SMEM[36864];
    _Float16* KsB = (_Float16*)SMEM;            // [kh][buf][32*72] halfs
    _Float16* VsB = (_Float16*)(SMEM + 18432);  // [kh][buf][64*36] halfs
    float* Red = (float*)SMEM;                  // epilogue: [4][64][33] f32

    const int bh = blockIdx.y, qb = blockIdx.x;
    const int tid = threadIdx.x;
    const int kh = tid >> 8;          // key half
    const int ltid = tid & 255;
    const int w = tid >> 6, wq = w & 3;
    const int lane = tid & 63;
    const int c = lane & 31, hf = lane >> 5;

    const _Float16* qbase = (const _Float16*)qh + ((size_t)bh * NSEQ + qb * 128) * DH;
    const _Float16* kbase = (const _Float16*)khg + ((size_t)bh * NSEQ + kh * 1024) * DH;
    const unsigned* vbase = vt2 + (size_t)bh * 32 * NSEQ + kh * 1024;

    // staging roles (per 256-thread half)
    const int skr = ltid >> 3, ssg = ltid & 7;      // K: row (key), 8-half chunk
    const int sdp = ltid >> 3, skq = (ltid & 7) * 4; // V: dim-pair, key*4 offset

    // stage tile 0 into buf 0
    {
        *(uint4*)&KsB[(kh * 2 + 0) * 2304 + skr * 72 + ssg * 8] =
            *(const uint4*)(kbase + skr * DH + ssg * 8);
        uint4 vr = *(const uint4*)(vbase + (size_t)sdp * NSEQ + skq);
        uint2 lo, hi;
        lo.x = PERM(vr.y, vr.x, 0x05040100u); hi.x = PERM(vr.y, vr.x, 0x07060302u);
        lo.y = PERM(vr.w, vr.z, 0x05040100u); hi.y = PERM(vr.w, vr.z, 0x07060302u);
        *(uint2*)&VsB[(kh * 2 + 0) * 2304 + (2 * sdp) * 36 + skq]     = lo;
        *(uint2*)&VsB[(kh * 2 + 0) * 2304 + (2 * sdp + 1) * 36 + skq] = hi;
    }

    // Q frags from global: B[k=dim][n=qrow]
    f16x8 qf[4];
    #pragma unroll
    for (int ks = 0; ks < 4; ++ks)
        qf[ks] = *(const f16x8*)(qbase + (wq * 32 + c) * DH + ks * 16 + hf * 8);

    f32x16v o[2];
    #pragma unroll
    for (int mt = 0; mt < 2; ++mt)
        #pragma unroll
        for (int r = 0; r < 16; ++r) o[mt][r] = 0.f;
    float lpart = 0.f;

    __syncthreads();

    for (int jt = 0; jt < 32; ++jt) {
        const int cur = jt & 1;
        const _Float16* KsCur = KsB + (kh * 2 + cur) * 2304;
        const _Float16* VsCur = VsB + (kh * 2 + cur) * 2304;

        uint4 kpre, vpre;
        if (jt + 1 < 32) {
            kpre = *(const uint4*)(kbase + (size_t)(jt + 1) * 32 * DH + skr * DH + ssg * 8);
            vpre = *(const uint4*)(vbase + (size_t)sdp * NSEQ + (jt + 1) * 32 + skq);
        }

        // S^T = K * Q^T (32 keys x 32 qrows), qrow = c, key = (r&3)+8*(r>>2)+4*hf
        f32x16v s;
        #pragma unroll
        for (int r = 0; r < 16; ++r) s[r] = 0.f;
        #pragma unroll
        for (int ks = 0; ks < 4; ++ks) {
            f16x8 ka = *(const f16x8*)&KsCur[c * 72 + ks * 16 + hf * 8];
            s = __builtin_amdgcn_mfma_f32_32x32x16_f16(ka, qf[ks], s, 0, 0, 0);
        }

        // exp2 (fixed max) + running denominator
        #pragma unroll
        for (int r = 0; r < 16; ++r) {
            float pv = EXP2F(s[r]);
            s[r] = pv;
            lpart += pv;
        }

        // O^T += V^T * P^T ; build B-frags in-register from C-layout
        #pragma unroll
        for (int kk = 0; kk < 2; ++kk) {
            unsigned P01 = pkrtz(s[kk * 8 + 0], s[kk * 8 + 1]);
            unsigned P23 = pkrtz(s[kk * 8 + 2], s[kk * 8 + 3]);
            unsigned P45 = pkrtz(s[kk * 8 + 4], s[kk * 8 + 5]);
            unsigned P67 = pkrtz(s[kk * 8 + 6], s[kk * 8 + 7]);
            unsigned x01 = (unsigned)__shfl_xor((int)P01, 32);
            unsigned x23 = (unsigned)__shfl_xor((int)P23, 32);
            unsigned x45 = (unsigned)__shfl_xor((int)P45, 32);
            unsigned x67 = (unsigned)__shfl_xor((int)P67, 32);
            union { unsigned u[4]; f16x8 v; } B;
            B.u[0] = hf ? x45 : P01;
            B.u[1] = hf ? x67 : P23;
            B.u[2] = hf ? P45 : x01;
            B.u[3] = hf ? P67 : x23;
            f16x8 va0 = *(const f16x8*)&VsCur[c * 36 + kk * 16 + hf * 8];
            f16x8 va1 = *(const f16x8*)&VsCur[(32 + c) * 36 + kk * 16 + hf * 8];
            o[0] = __builtin_amdgcn_mfma_f32_32x32x16_f16(va0, B.v, o[0], 0, 0, 0);
            o[1] = __builtin_amdgcn_mfma_f32_32x32x16_f16(va1, B.v, o[1], 0, 0, 0);
        }

        // commit prefetch to other buffer
        if (jt + 1 < 32) {
            _Float16* KsN = KsB + (kh * 2 + (1 - cur)) * 2304;
            _Float16* VsN = VsB + (kh * 2 + (1 - cur)) * 2304;
            *(uint4*)&KsN[skr * 72 + ssg * 8] = kpre;
            uint2 lo, hi;
            lo.x = PERM(kpre.y, kpre.x, 0u); // placeholder to keep regs tight (unused)
            lo.x = PERM(vpre.y, vpre.x, 0x05040100u); hi.x = PERM(vpre.y, vpre.x, 0x07060302u);
            lo.y = PERM(vpre.w, vpre.z, 0x05040100u); hi.y = PERM(vpre.w, vpre.z, 0x07060302u);
            *(uint2*)&VsN[(2 * sdp) * 36 + skq]     = lo;
            *(uint2*)&VsN[(2 * sdp + 1) * 36 + skq] = hi;
        }
        __syncthreads();
    }

    // ---- combine the two key-halves through LDS (sum of numerators + sums l) ----
    if (kh == 1) {
        float* r = Red + ((size_t)wq * 64 + lane) * 33;
        #pragma unroll
        for (int i = 0; i < 16; ++i) r[i] = o[0][i];
        #pragma unroll
        for (int i = 0; i < 16; ++i) r[16 + i] = o[1][i];
        r[32] = lpart;
    }
    __syncthreads();
    if (kh == 0) {
        const float* r = Red + ((size_t)wq * 64 + lane) * 33;
        #pragma unroll
        for (int i = 0; i < 16; ++i) o[0][i] += r[i];
        #pragma unroll
        for (int i = 0; i < 16; ++i) o[1][i] += r[16 + i];
        lpart += r[32];
        float ltot = lpart + __shfl_xor(lpart, 32);
        float invl = 1.0f / ltot;
        const int b = bh >> 4, h = bh & 15;
        const int pos = qb * 128 + wq * 32 + c;
        float* obase = out + ((size_t)b * NSEQ + pos) * (NH * DH) + h * DH;
        #pragma unroll
        for (int mt = 0; mt < 2; ++mt)
            #pragma unroll
            for (int g = 0; g < 4; ++g) {
                float4 r4 = make_float4(o[mt][g * 4 + 0] * invl, o[mt][g * 4 + 1] * invl,
                                        o[mt][g * 4 + 2] * invl, o[mt][g * 4 + 3] * invl);
                *(float4*)(obase + mt * 32 + g * 8 + hf * 4) = r4;
            }
    }
}

extern "C" void kernel_launch(void* const* d_in, const int* in_sizes, int n_in,
                              void* d_out, int out_size, void* d_ws, size_t ws_size,
                              hipStream_t stream) {
    const float* q  = (const float*)d_in[0];
    const float* k  = (const float*)d_in[1];
    const float* v  = (const float*)d_in[2];
    const float* qs = (const float*)d_in[3];
    const float* ks = (const float*)d_in[4];
    float* outp = (float*)d_out;

    unsigned* qh  = (unsigned*)d_ws;                 // 8 MB
    unsigned* kh  = qh + (size_t)BH * NSEQ * 32;     // 8 MB
    unsigned* vt2 = kh + (size_t)BH * NSEQ * 32;     // 8 MB

    prep_all<<<17408, 256, 0, stream>>>(q, k, v, qs, ks, qh, kh, vt2);
    attn_kernel<<<dim3(NSEQ / 128, BH), 512, 0, stream>>>(qh, kh, vt2, outp);
}